// Round 7
// baseline (247.105 us; speedup 1.0000x reference)
//
#include <hip/hip_runtime.h>

#define NS 32768
#define NE 4

typedef __attribute__((ext_vector_type(4))) float f32x4;
typedef __attribute__((ext_vector_type(8))) short bf16x8;

// fp32 -> bf16, round-to-nearest-even
__device__ __forceinline__ unsigned short f2bf(float f) {
    unsigned int u = __float_as_uint(f);
    u = (u + 0x7fffu + ((u >> 16) & 1u)) >> 16;
    return (unsigned short)u;
}

__device__ __forceinline__ int expert_of(const float4 yr) {
    int e = 0;
    if (yr.y > 0.5f) e = 1;
    else if (yr.z > 0.5f) e = 2;
    else if (yr.w > 0.5f) e = 3;
    return e;
}

// Prep A: blocks 0..15 transpose W -> Wt bf16; blocks 16..143 count experts
// per 256-sample chunk into bcnt[e][chunk]. Counts are block-exclusive ->
// no atomics, no memset needed.
__global__ void prep_count(const float* __restrict__ W,
                           unsigned short* __restrict__ Wt,
                           const float* __restrict__ y,
                           int* __restrict__ bcnt) {
    const int b = blockIdx.x;
    if (b < 16) {
        const float* w = W + (size_t)b * 16384;         // [c][k]
        unsigned short* wt = Wt + (size_t)b * 16384;    // [k][c]
        for (int i = threadIdx.x; i < 16384; i += 256) {
            int c = i & 127, k = i >> 7;
            wt[k * 128 + c] = f2bf(w[c * 128 + k]);
        }
        return;
    }
    __shared__ int c[4][4];                             // [wave][expert]
    const int blk = b - 16;                             // 0..127
    int n = blk * 256 + threadIdx.x;
    int e = expert_of(((const float4*)y)[n]);
    const int lane = threadIdx.x & 63;
    const int wv = threadIdx.x >> 6;
#pragma unroll
    for (int ee = 0; ee < NE; ++ee) {
        unsigned long long m = __ballot(e == ee);
        if (lane == 0) c[wv][ee] = __popcll(m);
    }
    __syncthreads();
    if (threadIdx.x < 4)
        bcnt[threadIdx.x * 128 + blk] = c[0][threadIdx.x] + c[1][threadIdx.x] +
                                        c[2][threadIdx.x] + c[3][threadIdx.x];
}

// Prep B: one block, 512 threads. Segmented exclusive scan of bcnt[4][128]
// -> boff[4][128]; also writes cnt[e] totals.
__global__ void prep_scan(const int* __restrict__ bcnt, int* __restrict__ boff,
                          int* __restrict__ cnt) {
    __shared__ int s[512];
    const int t = threadIdx.x;
    int v = bcnt[t];
    s[t] = v;
    __syncthreads();
    for (int d = 1; d < 512; d <<= 1) {
        int add = (t >= d) ? s[t - d] : 0;
        __syncthreads();
        s[t] += add;
        __syncthreads();
    }
    int seg = (t >= 128) ? s[(t >> 7) * 128 - 1] : 0;
    boff[t] = s[t] - v - seg;                 // exclusive within expert seg
    if ((t & 127) == 127) cnt[t >> 7] = s[t] - seg;
}

// Prep C: write idx sorted by n within each expert (block-order + wave-order
// + lane-prefix rank -> strictly increasing, fully deterministic).
__global__ void prep_fill(const float* __restrict__ y,
                          const int* __restrict__ boff, int* __restrict__ idx) {
    __shared__ int wcnt[4][4];                // [wave][expert]
    const int blk = blockIdx.x;
    int n = blk * 256 + threadIdx.x;
    int e = expert_of(((const float4*)y)[n]);
    const int lane = threadIdx.x & 63;
    const int wv = threadIdx.x >> 6;
    int rank = 0;
#pragma unroll
    for (int ee = 0; ee < NE; ++ee) {
        unsigned long long m = __ballot(e == ee);
        if (lane == 0) wcnt[wv][ee] = __popcll(m);
        if (e == ee) rank = __popcll(m & ((1ull << lane) - 1ull));
    }
    __syncthreads();
#pragma unroll
    for (int w = 0; w < 4; ++w)
        if (w < wv) rank += wcnt[w][e];
    idx[e * NS + boff[e * 128 + blk] + rank] = n;
}

// LDS: [0, 32768) weight panel bf16 [k=128][c=128], XOR-swizzled
// (byte ^= ((k & 7) << 4)) -> conflict-spread ds_read_b128 fragments.
// x is loaded DIRECTLY from global in MFMA B-fragment layout: lane (li,half)
// reads its own row li's floats [kk*32+half*8, +8) -- sorted idx makes the
// 16 rows of a wave-tile quasi-contiguous, so each instruction covers full
// cache lines (L2 merges the v0/v1 halves).
template <int L, int M>
__device__ __forceinline__ void gemm_body(
    int e, int bi, int nb, unsigned char* lds, const float* __restrict__ x,
    const unsigned short* __restrict__ Wt, const int* __restrict__ cnt,
    const int* __restrict__ idx, float* __restrict__ out) {
    const int rows_total = cnt[e] * M;

    // Stage weight panel once per block; contiguous 4 KB per instruction.
    {
        const unsigned char* wp =
            (const unsigned char*)(Wt + (size_t)(e * 4 + L) * 16384);
        const int t = threadIdx.x;
#pragma unroll
        for (int q = 0; q < 8; ++q) {
            int o = q * 4096 + t * 16;
            uint4 v = *(const uint4*)(wp + o);
            int so = o ^ (((o >> 8) & 7) << 4);   // o>>8 = k row (256 B rows)
            *(uint4*)(lds + so) = v;
        }
    }
    __syncthreads();

    const int lane = threadIdx.x & 63;
    const int wv = threadIdx.x >> 6;
    const int li = lane & 15;
    const int half = lane >> 4;   // 0..3

    for (int tile = bi; tile * 64 < rows_total; tile += nb) {
        int g = tile * 64 + wv * 16 + li;
        bool valid = g < rows_total;
        int gc = valid ? g : rows_total - 1;      // clamp for safe loads
        int pos = gc / M;                         // compile-time M -> magic
        int jj = gc - pos * M;
        int xrow = idx[e * NS + pos] * 16 + L * L + jj;

        // Direct fragment loads: 8 instructions, all in flight together.
        const float* xr = x + (size_t)xrow * 128 + half * 8;
        f32x4 v0[4], v1[4];
#pragma unroll
        for (int kk = 0; kk < 4; ++kk) {
            v0[kk] = *(const f32x4*)(xr + kk * 32);
            v1[kk] = *(const f32x4*)(xr + kk * 32 + 4);
        }
        bf16x8 bfrag[4];
#pragma unroll
        for (int kk = 0; kk < 4; ++kk) {
            bfrag[kk][0] = (short)f2bf(v0[kk].x);
            bfrag[kk][1] = (short)f2bf(v0[kk].y);
            bfrag[kk][2] = (short)f2bf(v0[kk].z);
            bfrag[kk][3] = (short)f2bf(v0[kk].w);
            bfrag[kk][4] = (short)f2bf(v1[kk].x);
            bfrag[kk][5] = (short)f2bf(v1[kk].y);
            bfrag[kk][6] = (short)f2bf(v1[kk].z);
            bfrag[kk][7] = (short)f2bf(v1[kk].w);
        }

        f32x4 acc[8];
#pragma unroll
        for (int t = 0; t < 8; ++t) acc[t] = (f32x4){0.f, 0.f, 0.f, 0.f};

#pragma unroll
        for (int kk = 0; kk < 4; ++kk) {
            int co = (kk * 64 + half * 16) ^ ((li & 7) << 4);
#pragma unroll
            for (int t = 0; t < 8; ++t) {
                bf16x8 afrag = *(const bf16x8*)(lds + (t * 16 + li) * 256 + co);
                acc[t] = __builtin_amdgcn_mfma_f32_16x16x32_bf16(afrag, bfrag[kk],
                                                                 acc[t], 0, 0, 0);
            }
        }

        if (valid) {
            float* orow = out + (size_t)xrow * 128;
            const float pw = 0.088388347648318447f;  // 1/sqrt(128)
#pragma unroll
            for (int t = 0; t < 8; ++t) {
                *(f32x4*)(orow + t * 16 + half * 4) = acc[t] * pw;
            }
        }
    }
}

// Static (e,l) partition: per e (512 blocks): l0:32, l1:96, l2:160, l3:224
// (proportional to 2l+1 -> ~4 tiles per block regardless of l).
// LDS now 32 KB -> 5 blocks/CU; VGPR <=128 via launch_bounds -> 16 waves/CU.
__global__ __launch_bounds__(256, 4) void gemm_main(
    const float* __restrict__ x, const unsigned short* __restrict__ Wt,
    const int* __restrict__ cnt, const int* __restrict__ idx,
    float* __restrict__ out) {
    __shared__ __align__(16) unsigned char lds[32768];
    const int b = blockIdx.x;
    const int e = b >> 9;
    const int r = b & 511;
    if (r < 32)       gemm_body<0, 1>(e, r,       32,  lds, x, Wt, cnt, idx, out);
    else if (r < 128) gemm_body<1, 3>(e, r - 32,  96,  lds, x, Wt, cnt, idx, out);
    else if (r < 288) gemm_body<2, 5>(e, r - 128, 160, lds, x, Wt, cnt, idx, out);
    else              gemm_body<3, 7>(e, r - 288, 224, lds, x, Wt, cnt, idx, out);
}

extern "C" void kernel_launch(void* const* d_in, const int* in_sizes, int n_in,
                              void* d_out, int out_size, void* d_ws,
                              size_t ws_size, hipStream_t stream) {
    const float* x = (const float*)d_in[0];
    const float* y = (const float*)d_in[1];
    const float* W = (const float*)d_in[2];
    float* out = (float*)d_out;

    char* ws = (char*)d_ws;
    int* cnt = (int*)ws;                                            // 16 B
    int* idx = (int*)(ws + 64);                                     // 512 KB
    unsigned short* Wt = (unsigned short*)(ws + 64 + NE * NS * 4);  // 512 KB
    int* bcnt = (int*)(ws + 64 + NE * NS * 4 + 16 * 16384 * 2);     // 2 KB
    int* boff = bcnt + 512;                                         // 2 KB

    prep_count<<<16 + 128, 256, 0, stream>>>(W, Wt, y, bcnt);
    prep_scan<<<1, 512, 0, stream>>>(bcnt, boff, cnt);
    prep_fill<<<128, 256, 0, stream>>>(y, boff, idx);
    gemm_main<<<2048, 256, 0, stream>>>(x, Wt, cnt, idx, out);
}

// Round 8
// 239.176 us; speedup vs baseline: 1.0332x; 1.0332x over previous
//
#include <hip/hip_runtime.h>

#define NS 32768
#define NE 4

typedef __attribute__((ext_vector_type(4))) float f32x4;
typedef __attribute__((ext_vector_type(8))) short bf16x8;

// fp32 -> bf16, round-to-nearest-even
__device__ __forceinline__ unsigned short f2bf(float f) {
    unsigned int u = __float_as_uint(f);
    u = (u + 0x7fffu + ((u >> 16) & 1u)) >> 16;
    return (unsigned short)u;
}

__device__ __forceinline__ int expert_of(const float4 yr) {
    int e = 0;
    if (yr.y > 0.5f) e = 1;
    else if (yr.z > 0.5f) e = 2;
    else if (yr.w > 0.5f) e = 3;
    return e;
}

// Prep A: blocks 0..15 transpose W -> Wt bf16; blocks 16..143 count experts
// per 256-sample chunk into bcnt[e][chunk] (block-exclusive, no atomics).
__global__ void prep_count(const float* __restrict__ W,
                           unsigned short* __restrict__ Wt,
                           const float* __restrict__ y,
                           int* __restrict__ bcnt) {
    const int b = blockIdx.x;
    if (b < 16) {
        const float* w = W + (size_t)b * 16384;         // [c][k]
        unsigned short* wt = Wt + (size_t)b * 16384;    // [k][c]
        for (int i = threadIdx.x; i < 16384; i += 256) {
            int c = i & 127, k = i >> 7;
            wt[k * 128 + c] = f2bf(w[c * 128 + k]);
        }
        return;
    }
    __shared__ int c[4][4];                             // [wave][expert]
    const int blk = b - 16;                             // 0..127
    int n = blk * 256 + threadIdx.x;
    int e = expert_of(((const float4*)y)[n]);
    const int lane = threadIdx.x & 63;
    const int wv = threadIdx.x >> 6;
#pragma unroll
    for (int ee = 0; ee < NE; ++ee) {
        unsigned long long m = __ballot(e == ee);
        if (lane == 0) c[wv][ee] = __popcll(m);
    }
    __syncthreads();
    if (threadIdx.x < 4)
        bcnt[threadIdx.x * 128 + blk] = c[0][threadIdx.x] + c[1][threadIdx.x] +
                                        c[2][threadIdx.x] + c[3][threadIdx.x];
}

// Prep B: one block, 512 threads. Segmented exclusive scan of bcnt[4][128]
// -> boff[4][128]; also writes cnt[e] totals.
__global__ void prep_scan(const int* __restrict__ bcnt, int* __restrict__ boff,
                          int* __restrict__ cnt) {
    __shared__ int s[512];
    const int t = threadIdx.x;
    int v = bcnt[t];
    s[t] = v;
    __syncthreads();
    for (int d = 1; d < 512; d <<= 1) {
        int add = (t >= d) ? s[t - d] : 0;
        __syncthreads();
        s[t] += add;
        __syncthreads();
    }
    int seg = (t >= 128) ? s[(t >> 7) * 128 - 1] : 0;
    boff[t] = s[t] - v - seg;                 // exclusive within expert seg
    if ((t & 127) == 127) cnt[t >> 7] = s[t] - seg;
}

// Prep C: write idx sorted by n within each expert (deterministic).
__global__ void prep_fill(const float* __restrict__ y,
                          const int* __restrict__ boff, int* __restrict__ idx) {
    __shared__ int wcnt[4][4];                // [wave][expert]
    const int blk = blockIdx.x;
    int n = blk * 256 + threadIdx.x;
    int e = expert_of(((const float4*)y)[n]);
    const int lane = threadIdx.x & 63;
    const int wv = threadIdx.x >> 6;
    int rank = 0;
#pragma unroll
    for (int ee = 0; ee < NE; ++ee) {
        unsigned long long m = __ballot(e == ee);
        if (lane == 0) wcnt[wv][ee] = __popcll(m);
        if (e == ee) rank = __popcll(m & ((1ull << lane) - 1ull));
    }
    __syncthreads();
#pragma unroll
    for (int w = 0; w < 4; ++w)
        if (w < wv) rank += wcnt[w][e];
    idx[e * NS + boff[e * 128 + blk] + rank] = n;
}

// --- pipelined tile helpers ---------------------------------------------
// Row base + 8 coalesced x loads (2 full 512-B rows per instruction).
template <int L, int M>
__device__ __forceinline__ void load_tile(
    const float* __restrict__ x, const int* __restrict__ idx, int e,
    int rows_total, int tile, int wv, int li, int i5, int c32,
    int& xrow, bool& valid, f32x4* bv) {
    int g = tile * 64 + wv * 16 + li;
    valid = g < rows_total;
    int gc = valid ? g : rows_total - 1;      // clamp for safe loads
    int pos = gc / M;                         // compile-time M -> magic mul
    int jj = gc - pos * M;
    xrow = idx[e * NS + pos] * 16 + L * L + jj;
#pragma unroll
    for (int q = 0; q < 8; ++q) {
        int nr = __shfl(xrow, 2 * q + i5);    // lane r holds row r's base
        bv[q] = *(const f32x4*)(x + (size_t)nr * 128 + c32 * 4);
    }
}

// Pack -> LDS -> fragments -> MFMA -> store (wave-private, no barriers).
__device__ __forceinline__ void compute_tile(
    const unsigned char* __restrict__ lds, unsigned char* __restrict__ xl,
    const f32x4* bv, int xrow, bool valid, int li, int half, int i5, int c32,
    float* __restrict__ out) {
#pragma unroll
    for (int q = 0; q < 8; ++q) {
        int tr = 2 * q + i5;
        unsigned int p0 = (unsigned int)f2bf(bv[q].x) |
                          ((unsigned int)f2bf(bv[q].y) << 16);
        unsigned int p1 = (unsigned int)f2bf(bv[q].z) |
                          ((unsigned int)f2bf(bv[q].w) << 16);
        uint2 pk; pk.x = p0; pk.y = p1;
        int off = (c32 * 8) ^ ((tr & 7) << 4);
        *(uint2*)(xl + tr * 256 + off) = pk;
    }

    f32x4 acc[8];
#pragma unroll
    for (int t = 0; t < 8; ++t) acc[t] = (f32x4){0.f, 0.f, 0.f, 0.f};

#pragma unroll
    for (int kk = 0; kk < 4; ++kk) {
        int co = (kk * 64 + half * 16) ^ ((li & 7) << 4);
        bf16x8 bfrag = *(const bf16x8*)(xl + li * 256 + co);
#pragma unroll
        for (int t = 0; t < 8; ++t) {
            bf16x8 afrag = *(const bf16x8*)(lds + (t * 16 + li) * 256 + co);
            acc[t] = __builtin_amdgcn_mfma_f32_16x16x32_bf16(afrag, bfrag,
                                                             acc[t], 0, 0, 0);
        }
    }

    if (valid) {
        float* orow = out + (size_t)xrow * 128;
        const float pw = 0.088388347648318447f;  // 1/sqrt(128)
#pragma unroll
        for (int t = 0; t < 8; ++t) {
            *(f32x4*)(orow + t * 16 + half * 4) = acc[t] * pw;
        }
    }
}

// LDS: [0,32768) weight panel bf16 [k=128][c=128] XOR-swizzled;
//      [32768,49152) per-wave x tiles [16][128] bf16, swizzled.
// 2-deep pipeline, UNCONDITIONAL clamped prefetch: the next-tile loads are
// always issued (tail re-reads an L2-hot tile), so outstanding-vmem counts
// are branch-independent and the compiler emits counted s_waitcnt vmcnt(N)
// instead of draining to 0 at a conditional join (the R5 mistake).
template <int L, int M>
__device__ __forceinline__ void gemm_body(
    int e, int bi, int nb, unsigned char* lds, const float* __restrict__ x,
    const unsigned short* __restrict__ Wt, const int* __restrict__ cnt,
    const int* __restrict__ idx, float* __restrict__ out) {
    const int rows_total = cnt[e] * M;
    const int nt = (rows_total + 63) >> 6;    // total tiles for (e,L)

    // Stage weight panel once per block; contiguous 4 KB per instruction.
    {
        const unsigned char* wp =
            (const unsigned char*)(Wt + (size_t)(e * 4 + L) * 16384);
        const int t = threadIdx.x;
#pragma unroll
        for (int q = 0; q < 8; ++q) {
            int o = q * 4096 + t * 16;
            uint4 v = *(const uint4*)(wp + o);
            int so = o ^ (((o >> 8) & 7) << 4);   // o>>8 = k row (256 B rows)
            *(uint4*)(lds + so) = v;
        }
    }
    __syncthreads();

    const int lane = threadIdx.x & 63;
    const int wv = threadIdx.x >> 6;
    const int li = lane & 15;
    const int half = lane >> 4;
    const int i5 = lane >> 5;
    const int c32 = lane & 31;
    unsigned char* xl = lds + 32768 + wv * 4096;  // wave-private x tile

    int tA = bi;
    if (tA >= nt) return;

    int xrowA, xrowB;
    bool vA, vB;
    f32x4 bvA[8], bvB[8];

    load_tile<L, M>(x, idx, e, rows_total, tA, wv, li, i5, c32, xrowA, vA, bvA);
    for (;;) {
        int tB = tA + nb;
        bool hB = tB < nt;
        load_tile<L, M>(x, idx, e, rows_total, hB ? tB : tA, wv, li, i5, c32,
                        xrowB, vB, bvB);
        compute_tile(lds, xl, bvA, xrowA, vA, li, half, i5, c32, out);
        if (!hB) break;
        int tC = tB + nb;
        bool hC = tC < nt;
        load_tile<L, M>(x, idx, e, rows_total, hC ? tC : tB, wv, li, i5, c32,
                        xrowA, vA, bvA);
        compute_tile(lds, xl, bvB, xrowB, vB, li, half, i5, c32, out);
        if (!hC) break;
        tA = tC;
    }
}

// Static (e,l) partition: per e (512 blocks): l0:32, l1:96, l2:160, l3:224
// (proportional to 2l+1 -> ~4 tiles per block regardless of l).
__global__ __launch_bounds__(256, 3) void gemm_main(
    const float* __restrict__ x, const unsigned short* __restrict__ Wt,
    const int* __restrict__ cnt, const int* __restrict__ idx,
    float* __restrict__ out) {
    __shared__ __align__(16) unsigned char lds[49152];
    const int b = blockIdx.x;
    const int e = b >> 9;
    const int r = b & 511;
    if (r < 32)       gemm_body<0, 1>(e, r,       32,  lds, x, Wt, cnt, idx, out);
    else if (r < 128) gemm_body<1, 3>(e, r - 32,  96,  lds, x, Wt, cnt, idx, out);
    else if (r < 288) gemm_body<2, 5>(e, r - 128, 160, lds, x, Wt, cnt, idx, out);
    else              gemm_body<3, 7>(e, r - 288, 224, lds, x, Wt, cnt, idx, out);
}

extern "C" void kernel_launch(void* const* d_in, const int* in_sizes, int n_in,
                              void* d_out, int out_size, void* d_ws,
                              size_t ws_size, hipStream_t stream) {
    const float* x = (const float*)d_in[0];
    const float* y = (const float*)d_in[1];
    const float* W = (const float*)d_in[2];
    float* out = (float*)d_out;

    char* ws = (char*)d_ws;
    int* cnt = (int*)ws;                                            // 16 B
    int* idx = (int*)(ws + 64);                                     // 512 KB
    unsigned short* Wt = (unsigned short*)(ws + 64 + NE * NS * 4);  // 512 KB
    int* bcnt = (int*)(ws + 64 + NE * NS * 4 + 16 * 16384 * 2);     // 2 KB
    int* boff = bcnt + 512;                                         // 2 KB

    prep_count<<<16 + 128, 256, 0, stream>>>(W, Wt, y, bcnt);
    prep_scan<<<1, 512, 0, stream>>>(bcnt, boff, cnt);
    prep_fill<<<128, 256, 0, stream>>>(y, boff, idx);
    gemm_main<<<2048, 256, 0, stream>>>(x, Wt, cnt, idx, out);
}

// Round 9
// 138.312 us; speedup vs baseline: 1.7866x; 1.7292x over previous
//
#include <hip/hip_runtime.h>

#define NS 32768
#define NE 4

typedef __attribute__((ext_vector_type(4))) float f32x4;
typedef __attribute__((ext_vector_type(8))) short bf16x8;

// fp32 -> bf16, round-to-nearest-even
__device__ __forceinline__ unsigned short f2bf(float f) {
    unsigned int u = __float_as_uint(f);
    u = (u + 0x7fffu + ((u >> 16) & 1u)) >> 16;
    return (unsigned short)u;
}

__device__ __forceinline__ int expert_of(const float4 yr) {
    int e = 0;
    if (yr.y > 0.5f) e = 1;
    else if (yr.z > 0.5f) e = 2;
    else if (yr.w > 0.5f) e = 3;
    return e;
}

// Prep A: blocks 0..15 transpose W -> Wt bf16; blocks 16..143 count experts
// per 256-sample chunk into bcnt[e][chunk] (block-exclusive, no atomics).
__global__ void prep_count(const float* __restrict__ W,
                           unsigned short* __restrict__ Wt,
                           const float* __restrict__ y,
                           int* __restrict__ bcnt) {
    const int b = blockIdx.x;
    if (b < 16) {
        const float* w = W + (size_t)b * 16384;         // [c][k]
        unsigned short* wt = Wt + (size_t)b * 16384;    // [k][c]
        for (int i = threadIdx.x; i < 16384; i += 256) {
            int c = i & 127, k = i >> 7;
            wt[k * 128 + c] = f2bf(w[c * 128 + k]);
        }
        return;
    }
    __shared__ int c[4][4];                             // [wave][expert]
    const int blk = b - 16;                             // 0..127
    int n = blk * 256 + threadIdx.x;
    int e = expert_of(((const float4*)y)[n]);
    const int lane = threadIdx.x & 63;
    const int wv = threadIdx.x >> 6;
#pragma unroll
    for (int ee = 0; ee < NE; ++ee) {
        unsigned long long m = __ballot(e == ee);
        if (lane == 0) c[wv][ee] = __popcll(m);
    }
    __syncthreads();
    if (threadIdx.x < 4)
        bcnt[threadIdx.x * 128 + blk] = c[0][threadIdx.x] + c[1][threadIdx.x] +
                                        c[2][threadIdx.x] + c[3][threadIdx.x];
}

// Prep B: one block, 512 threads. Segmented exclusive scan of bcnt[4][128]
// -> boff[4][128]; also writes cnt[e] totals.
__global__ void prep_scan(const int* __restrict__ bcnt, int* __restrict__ boff,
                          int* __restrict__ cnt) {
    __shared__ int s[512];
    const int t = threadIdx.x;
    int v = bcnt[t];
    s[t] = v;
    __syncthreads();
    for (int d = 1; d < 512; d <<= 1) {
        int add = (t >= d) ? s[t - d] : 0;
        __syncthreads();
        s[t] += add;
        __syncthreads();
    }
    int seg = (t >= 128) ? s[(t >> 7) * 128 - 1] : 0;
    boff[t] = s[t] - v - seg;                 // exclusive within expert seg
    if ((t & 127) == 127) cnt[t >> 7] = s[t] - seg;
}

// Prep C: write idx sorted by n within each expert (deterministic).
__global__ void prep_fill(const float* __restrict__ y,
                          const int* __restrict__ boff, int* __restrict__ idx) {
    __shared__ int wcnt[4][4];                // [wave][expert]
    const int blk = blockIdx.x;
    int n = blk * 256 + threadIdx.x;
    int e = expert_of(((const float4*)y)[n]);
    const int lane = threadIdx.x & 63;
    const int wv = threadIdx.x >> 6;
    int rank = 0;
#pragma unroll
    for (int ee = 0; ee < NE; ++ee) {
        unsigned long long m = __ballot(e == ee);
        if (lane == 0) wcnt[wv][ee] = __popcll(m);
        if (e == ee) rank = __popcll(m & ((1ull << lane) - 1ull));
    }
    __syncthreads();
#pragma unroll
    for (int w = 0; w < 4; ++w)
        if (w < wv) rank += wcnt[w][e];
    idx[e * NS + boff[e * 128 + blk] + rank] = n;
}

// LDS layout: [0, 32768)  weight panel bf16 [k=128][c=128], XOR-swizzled
//             [32768, 65536) per-wave x tiles bf16 [16 rows][c=128], swizzled
// Swizzle: byte ^= ((row & 7) << 4)  -> conflict-free ds_read_b128 fragments.
// 512-thread blocks: 8 waves share one weight panel; 64 KB LDS -> 2 blocks/CU
// -> 16 waves/CU (vs 12 in the 256-thread variant) for latency hiding.
template <int L, int M>
__device__ __forceinline__ void gemm_body(
    int e, int bi, int nb, unsigned char* lds, const float* __restrict__ x,
    const unsigned short* __restrict__ Wt, const int* __restrict__ cnt,
    const int* __restrict__ idx, float* __restrict__ out) {
    const int rows_total = cnt[e] * M;

    // Stage weight panel once per block; contiguous 8 KB per instruction.
    {
        const unsigned char* wp =
            (const unsigned char*)(Wt + (size_t)(e * 4 + L) * 16384);
        const int t = threadIdx.x;
#pragma unroll
        for (int q = 0; q < 4; ++q) {
            int o = q * 8192 + t * 16;
            uint4 v = *(const uint4*)(wp + o);
            int so = o ^ (((o >> 8) & 7) << 4);   // o>>8 = k row (256 B rows)
            *(uint4*)(lds + so) = v;
        }
    }
    __syncthreads();

    const int lane = threadIdx.x & 63;
    const int wv = threadIdx.x >> 6;  // 0..7
    const int li = lane & 15;
    const int half = lane >> 4;   // 0..3
    const int i5 = lane >> 5;     // 0..1
    const int c32 = lane & 31;
    unsigned char* xl = lds + 32768 + wv * 4096;  // this wave's private x tile

    // One tile-iteration covers 128 rows (8 waves x 16 rows).
    for (int tile = bi; tile * 128 < rows_total; tile += nb) {
        int g = tile * 128 + wv * 16 + li;
        bool valid = g < rows_total;
        int gc = valid ? g : rows_total - 1;      // clamp for safe loads
        int pos = gc / M;                         // compile-time M
        int jj = gc - pos * M;
        int xrow = idx[e * NS + pos] * 16 + L * L + jj;

        // Stage 16 rows: instr q covers rows 2q,2q+1 fully contiguous.
        f32x4 bv[8];
#pragma unroll
        for (int q = 0; q < 8; ++q) {
            int tr = 2 * q + i5;
            int nr = __shfl(xrow, tr);            // lane tr holds row tr's base
            bv[q] = *(const f32x4*)(x + (size_t)nr * 128 + c32 * 4);
        }
#pragma unroll
        for (int q = 0; q < 8; ++q) {
            int tr = 2 * q + i5;
            unsigned int p0 = (unsigned int)f2bf(bv[q].x) |
                              ((unsigned int)f2bf(bv[q].y) << 16);
            unsigned int p1 = (unsigned int)f2bf(bv[q].z) |
                              ((unsigned int)f2bf(bv[q].w) << 16);
            uint2 pk; pk.x = p0; pk.y = p1;
            int off = (c32 * 8) ^ ((tr & 7) << 4);
            *(uint2*)(xl + tr * 256 + off) = pk;
        }

        f32x4 acc[8];
#pragma unroll
        for (int t = 0; t < 8; ++t) acc[t] = (f32x4){0.f, 0.f, 0.f, 0.f};

#pragma unroll
        for (int kk = 0; kk < 4; ++kk) {
            int co = (kk * 64 + half * 16) ^ ((li & 7) << 4);
            bf16x8 bfrag = *(const bf16x8*)(xl + li * 256 + co);
#pragma unroll
            for (int t = 0; t < 8; ++t) {
                bf16x8 afrag = *(const bf16x8*)(lds + (t * 16 + li) * 256 + co);
                acc[t] = __builtin_amdgcn_mfma_f32_16x16x32_bf16(afrag, bfrag,
                                                                 acc[t], 0, 0, 0);
            }
        }

        if (valid) {
            float* orow = out + (size_t)xrow * 128;
            const float pw = 0.088388347648318447f;  // 1/sqrt(128)
#pragma unroll
            for (int t = 0; t < 8; ++t) {
                *(f32x4*)(orow + t * 16 + half * 4) = acc[t] * pw;
            }
        }
    }
}

// Static (e,l) partition: per e (256 blocks): l0:16, l1:48, l2:80, l3:112
// (proportional to 2l+1 -> ~4 tile-iterations per block regardless of l).
__global__ __launch_bounds__(512, 2) void gemm_main(
    const float* __restrict__ x, const unsigned short* __restrict__ Wt,
    const int* __restrict__ cnt, const int* __restrict__ idx,
    float* __restrict__ out) {
    __shared__ __align__(16) unsigned char lds[65536];
    const int b = blockIdx.x;
    const int e = b >> 8;
    const int r = b & 255;
    if (r < 16)       gemm_body<0, 1>(e, r,       16,  lds, x, Wt, cnt, idx, out);
    else if (r < 64)  gemm_body<1, 3>(e, r - 16,  48,  lds, x, Wt, cnt, idx, out);
    else if (r < 144) gemm_body<2, 5>(e, r - 64,  80,  lds, x, Wt, cnt, idx, out);
    else              gemm_body<3, 7>(e, r - 144, 112, lds, x, Wt, cnt, idx, out);
}

extern "C" void kernel_launch(void* const* d_in, const int* in_sizes, int n_in,
                              void* d_out, int out_size, void* d_ws,
                              size_t ws_size, hipStream_t stream) {
    const float* x = (const float*)d_in[0];
    const float* y = (const float*)d_in[1];
    const float* W = (const float*)d_in[2];
    float* out = (float*)d_out;

    char* ws = (char*)d_ws;
    int* cnt = (int*)ws;                                            // 16 B
    int* idx = (int*)(ws + 64);                                     // 512 KB
    unsigned short* Wt = (unsigned short*)(ws + 64 + NE * NS * 4);  // 512 KB
    int* bcnt = (int*)(ws + 64 + NE * NS * 4 + 16 * 16384 * 2);     // 2 KB
    int* boff = bcnt + 512;                                         // 2 KB

    prep_count<<<16 + 128, 256, 0, stream>>>(W, Wt, y, bcnt);
    prep_scan<<<1, 512, 0, stream>>>(bcnt, boff, cnt);
    prep_fill<<<128, 256, 0, stream>>>(y, boff, idx);
    gemm_main<<<1024, 512, 0, stream>>>(x, Wt, cnt, idx, out);
}

// Round 11
// 134.720 us; speedup vs baseline: 1.8342x; 1.0267x over previous
//
#include <hip/hip_runtime.h>

#define NS 32768
#define NE 4

typedef __attribute__((ext_vector_type(4))) float f32x4;
typedef __attribute__((ext_vector_type(8))) short bf16x8;

// fp32 -> bf16, round-to-nearest-even
__device__ __forceinline__ unsigned short f2bf(float f) {
    unsigned int u = __float_as_uint(f);
    u = (u + 0x7fffu + ((u >> 16) & 1u)) >> 16;
    return (unsigned short)u;
}

__device__ __forceinline__ int expert_of(const float4 yr) {
    int e = 0;
    if (yr.y > 0.5f) e = 1;
    else if (yr.z > 0.5f) e = 2;
    else if (yr.w > 0.5f) e = 3;
    return e;
}

// Prep A: blocks 0..15 transpose W -> Wt bf16; blocks 16..143 count experts
// per 256-sample chunk into bcnt[e][chunk] (block-exclusive, no atomics).
__global__ void prep_count(const float* __restrict__ W,
                           unsigned short* __restrict__ Wt,
                           const float* __restrict__ y,
                           int* __restrict__ bcnt) {
    const int b = blockIdx.x;
    if (b < 16) {
        const float* w = W + (size_t)b * 16384;         // [c][k]
        unsigned short* wt = Wt + (size_t)b * 16384;    // [k][c]
        for (int i = threadIdx.x; i < 16384; i += 256) {
            int c = i & 127, k = i >> 7;
            wt[k * 128 + c] = f2bf(w[c * 128 + k]);
        }
        return;
    }
    __shared__ int c[4][4];                             // [wave][expert]
    const int blk = b - 16;                             // 0..127
    int n = blk * 256 + threadIdx.x;
    int e = expert_of(((const float4*)y)[n]);
    const int lane = threadIdx.x & 63;
    const int wv = threadIdx.x >> 6;
#pragma unroll
    for (int ee = 0; ee < NE; ++ee) {
        unsigned long long m = __ballot(e == ee);
        if (lane == 0) c[wv][ee] = __popcll(m);
    }
    __syncthreads();
    if (threadIdx.x < 4)
        bcnt[threadIdx.x * 128 + blk] = c[0][threadIdx.x] + c[1][threadIdx.x] +
                                        c[2][threadIdx.x] + c[3][threadIdx.x];
}

// Prep B (merged scan+fill): each block computes its own expert offsets by
// wave-reducing bcnt directly (wave w = expert w), then writes idx sorted by
// n within each expert (deterministic). Block 0 also writes cnt totals.
__global__ void prep_fill(const float* __restrict__ y,
                          const int* __restrict__ bcnt, int* __restrict__ idx,
                          int* __restrict__ cnt) {
    __shared__ int sh_boff[4];
    __shared__ int wcnt[4][4];                // [wave][expert]
    const int blk = blockIdx.x;               // 0..127
    const int lane = threadIdx.x & 63;
    const int wv = threadIdx.x >> 6;          // 0..3 == expert for the scan

    // Per-expert exclusive offset for this block + totals (lanes 0..63 cover
    // chunks j and j+64).
    {
        int c0 = bcnt[wv * 128 + lane];
        int c1 = bcnt[wv * 128 + 64 + lane];
        int part = ((lane < blk) ? c0 : 0) + ((lane + 64 < blk) ? c1 : 0);
        int tot = c0 + c1;
#pragma unroll
        for (int d = 1; d < 64; d <<= 1) {
            part += __shfl_xor(part, d);
            tot += __shfl_xor(tot, d);
        }
        if (lane == 0) {
            sh_boff[wv] = part;
            if (blk == 0) cnt[wv] = tot;
        }
    }

    int n = blk * 256 + threadIdx.x;
    int e = expert_of(((const float4*)y)[n]);
    int rank = 0;
#pragma unroll
    for (int ee = 0; ee < NE; ++ee) {
        unsigned long long m = __ballot(e == ee);
        if (lane == 0) wcnt[wv][ee] = __popcll(m);
        if (e == ee) rank = __popcll(m & ((1ull << lane) - 1ull));
    }
    __syncthreads();
#pragma unroll
    for (int w = 0; w < 4; ++w)
        if (w < wv) rank += wcnt[w][e];
    idx[e * NS + sh_boff[e] + rank] = n;
}

// LDS layout: [0, 32768)  weight panel bf16 [k=128][c=128], XOR-swizzled
//             [32768, 65536) per-wave x tiles bf16 [16 rows][c=128], swizzled
// Swizzle: byte ^= ((row & 7) << 4)  -> conflict-free ds_read_b128 fragments.
// 512-thread blocks: 8 waves share one weight panel; 64 KB LDS -> 2 blocks/CU
// -> 16 waves/CU.
template <int L, int M>
__device__ __forceinline__ void gemm_body(
    int e, int bi, int nb, unsigned char* lds, const float* __restrict__ x,
    const unsigned short* __restrict__ Wt, const int* __restrict__ cnt,
    const int* __restrict__ idx, float* __restrict__ out) {
    const int rows_total = cnt[e] * M;

    // Stage weight panel once per block; contiguous 8 KB per instruction.
    {
        const unsigned char* wp =
            (const unsigned char*)(Wt + (size_t)(e * 4 + L) * 16384);
        const int t = threadIdx.x;
#pragma unroll
        for (int q = 0; q < 4; ++q) {
            int o = q * 8192 + t * 16;
            uint4 v = *(const uint4*)(wp + o);
            int so = o ^ (((o >> 8) & 7) << 4);   // o>>8 = k row (256 B rows)
            *(uint4*)(lds + so) = v;
        }
    }
    __syncthreads();

    const int lane = threadIdx.x & 63;
    const int wv = threadIdx.x >> 6;  // 0..7
    const int li = lane & 15;
    const int half = lane >> 4;   // 0..3
    const int i5 = lane >> 5;     // 0..1
    const int c32 = lane & 31;
    const int* idxe = idx + e * NS;
    unsigned char* xl = lds + 32768 + wv * 4096;  // this wave's private x tile

    // One tile-iteration covers 128 rows (8 waves x 16 rows).
    for (int tile = bi; tile * 128 < rows_total; tile += nb) {
        const int gbase = tile * 128 + wv * 16;

        // Per-lane epilogue row (lane li owns gathered row gbase+li).
        int g = gbase + li;
        bool valid = g < rows_total;
        int gc = valid ? g : rows_total - 1;      // clamp for safe loads
        int pos = gc / M;                         // compile-time M -> magic
        int jj = gc - pos * M;
        int xrow = idxe[pos] * 16 + L * L + jj;

        // Stage 16 rows: instr q covers rows 2q,2q+1 fully contiguous.
        // Independent idx loads per q (all hit 1-2 L1-hot lines) ->
        // 8 parallel idx->x address chains, no bpermute.
        f32x4 bv[8];
#pragma unroll
        for (int q = 0; q < 8; ++q) {
            int gt = gbase + 2 * q + i5;
            int gtc = gt < rows_total ? gt : rows_total - 1;
            int p = gtc / M;
            int jq = gtc - p * M;
            int nr = idxe[p] * 16 + L * L + jq;
            bv[q] = *(const f32x4*)(x + (size_t)nr * 128 + c32 * 4);
        }
#pragma unroll
        for (int q = 0; q < 8; ++q) {
            int tr = 2 * q + i5;
            unsigned int p0 = (unsigned int)f2bf(bv[q].x) |
                              ((unsigned int)f2bf(bv[q].y) << 16);
            unsigned int p1 = (unsigned int)f2bf(bv[q].z) |
                              ((unsigned int)f2bf(bv[q].w) << 16);
            uint2 pk; pk.x = p0; pk.y = p1;
            int off = (c32 * 8) ^ ((tr & 7) << 4);
            *(uint2*)(xl + tr * 256 + off) = pk;
        }

        f32x4 acc[8];
#pragma unroll
        for (int t = 0; t < 8; ++t) acc[t] = (f32x4){0.f, 0.f, 0.f, 0.f};

#pragma unroll
        for (int kk = 0; kk < 4; ++kk) {
            int co = (kk * 64 + half * 16) ^ ((li & 7) << 4);
            bf16x8 bfrag = *(const bf16x8*)(xl + li * 256 + co);
#pragma unroll
            for (int t = 0; t < 8; ++t) {
                bf16x8 afrag = *(const bf16x8*)(lds + (t * 16 + li) * 256 + co);
                acc[t] = __builtin_amdgcn_mfma_f32_16x16x32_bf16(afrag, bfrag,
                                                                 acc[t], 0, 0, 0);
            }
        }

        if (valid) {
            float* orow = out + (size_t)xrow * 128;
            const float pw = 0.088388347648318447f;  // 1/sqrt(128)
#pragma unroll
            for (int t = 0; t < 8; ++t) {
                *(f32x4*)(orow + t * 16 + half * 4) = acc[t] * pw;
            }
        }
    }
}

// Static (e,l) partition: per e (256 blocks): l0:16, l1:48, l2:80, l3:112
// (proportional to 2l+1 -> ~4 tile-iterations per block regardless of l).
__global__ __launch_bounds__(512, 2) void gemm_main(
    const float* __restrict__ x, const unsigned short* __restrict__ Wt,
    const int* __restrict__ cnt, const int* __restrict__ idx,
    float* __restrict__ out) {
    __shared__ __align__(16) unsigned char lds[65536];
    const int b = blockIdx.x;
    const int e = b >> 8;
    const int r = b & 255;
    if (r < 16)       gemm_body<0, 1>(e, r,       16,  lds, x, Wt, cnt, idx, out);
    else if (r < 64)  gemm_body<1, 3>(e, r - 16,  48,  lds, x, Wt, cnt, idx, out);
    else if (r < 144) gemm_body<2, 5>(e, r - 64,  80,  lds, x, Wt, cnt, idx, out);
    else              gemm_body<3, 7>(e, r - 144, 112, lds, x, Wt, cnt, idx, out);
}

extern "C" void kernel_launch(void* const* d_in, const int* in_sizes, int n_in,
                              void* d_out, int out_size, void* d_ws,
                              size_t ws_size, hipStream_t stream) {
    const float* x = (const float*)d_in[0];
    const float* y = (const float*)d_in[1];
    const float* W = (const float*)d_in[2];
    float* out = (float*)d_out;

    char* ws = (char*)d_ws;
    int* cnt = (int*)ws;                                            // 16 B
    int* idx = (int*)(ws + 64);                                     // 512 KB
    unsigned short* Wt = (unsigned short*)(ws + 64 + NE * NS * 4);  // 512 KB
    int* bcnt = (int*)(ws + 64 + NE * NS * 4 + 16 * 16384 * 2);     // 2 KB

    prep_count<<<16 + 128, 256, 0, stream>>>(W, Wt, y, bcnt);
    prep_fill<<<128, 256, 0, stream>>>(y, bcnt, idx, cnt);
    gemm_main<<<1024, 512, 0, stream>>>(x, Wt, cnt, idx, out);
}